// Round 1
// baseline (1257.360 us; speedup 1.0000x reference)
//
#include <hip/hip_runtime.h>
#include <math.h>

// Problem dims (fixed by setup_inputs)
#define B_SZ 256
#define D_SZ 512
#define K_SZ 128000
#define N_SZ 100000
#define NBLK (K_SZ / 64)   // 2000 gemm blocks, 64 cols each

// Workspace layout (bytes).
#define OFF_T     0UL          // t_f32      [256*512] f32
#define OFF_Q     524288UL     // q_f32      [256*512] f32
#define OFF_TH    1048576UL    // t_f16      [256*512] f16
#define OFF_CTH   1310720UL    // ct_f16     [256*512] f16
#define OFF_NPQ   1572864UL    // new_pq     [100000] i32
#define OFF_TPROW 1973248UL    // tp_row     [128000] i32
#define OFF_UN    2485248UL    // un_idx     [256*5] i32
#define OFF_IDXP  2490880UL    // idxp       [256*10] i32
#define OFF_SC    2501632UL    // cand       [256][2000][<=10] u64 (max 41 MB)

typedef __attribute__((ext_vector_type(4))) float    f32x4;
typedef __attribute__((ext_vector_type(8))) _Float16 f16x8;

// ---------------- block-wide sum over 256 threads ----------------
__device__ __forceinline__ float block_sum(float v, float* red) {
  #pragma unroll
  for (int o = 32; o > 0; o >>= 1) v += __shfl_down(v, o, 64);
  const int w = threadIdx.x >> 6;
  const int l = threadIdx.x & 63;
  __syncthreads();                 // protect red[] reuse across calls
  if (l == 0) red[w] = v;
  __syncthreads();
  return red[0] + red[1] + red[2] + red[3];
}

// ---------------- prep: normalize q,t; gather ct_prime ----------------
__global__ __launch_bounds__(256) void prep_rows_kernel(
    const float* __restrict__ query, const float* __restrict__ ctar,
    const float* __restrict__ pool, const int* __restrict__ pool_qindex,
    const int* __restrict__ indices,
    float* __restrict__ t_f32, float* __restrict__ q_f32,
    _Float16* __restrict__ t_f16, _Float16* __restrict__ ct_f16)
{
  __shared__ float red[4];
  const int b = blockIdx.x, tid = threadIdx.x;
  const long base = (long)b * D_SZ;
  float x0 = query[base + tid], x1 = query[base + 256 + tid];
  float y0 = ctar[base + tid],  y1 = ctar[base + 256 + tid];
  float sq = block_sum(x0 * x0 + x1 * x1, red);
  float st = block_sum(y0 * y0 + y1 * y1, red);
  float rq = 1.f / sqrtf(sq);
  float rt = 1.f / sqrtf(st);
  q_f32[base + tid] = x0 * rq; q_f32[base + 256 + tid] = x1 * rq;
  float t0 = y0 * rt, t1 = y1 * rt;
  t_f32[base + tid] = t0; t_f32[base + 256 + tid] = t1;
  t_f16[base + tid] = (_Float16)t0; t_f16[base + 256 + tid] = (_Float16)t1;
  // ct_prime[b] = pool[1 - pq[indices[b]], indices[b]] (post-flip slot == un-written slot)
  int i = indices[b];
  int slot = 1 - pool_qindex[i];
  const float* pr = pool + ((long)slot * N_SZ + i) * D_SZ;
  ct_f16[base + tid] = (_Float16)pr[tid];
  ct_f16[base + 256 + tid] = (_Float16)pr[tid + 256];
}

__global__ void prep_newpq_kernel(const int* __restrict__ pq, int* __restrict__ new_pq) {
  int i = blockIdx.x * 256 + threadIdx.x;
  if (i < N_SZ) new_pq[i] = pq[i];
}

__global__ void prep_flip_kernel(const int* __restrict__ pq, const int* __restrict__ indices,
                                 int* __restrict__ new_pq) {
  int i = indices[threadIdx.x];           // 1 block x 256; dup indices write same value
  new_pq[i] = 1 - pq[i];
}

__global__ void prep_tprow_kernel(const int* __restrict__ new_pq,
                                  const int* __restrict__ index_queue,
                                  const int* __restrict__ indices,
                                  int* __restrict__ tp_row) {
  int k = blockIdx.x * 256 + threadIdx.x; // 500 blocks -> exactly 128000
  int i = (k < B_SZ) ? indices[k] : index_queue[k];
  tp_row[k] = new_pq[i] * N_SZ + i;
}

// ---------------- fused GEMM + per-block top-K candidates ----------------
// scores[b][k] = rowA(b) . rowB(k)
// MODE 0: A = t_f16, B(k) = (k<256 ? t : queue[k])    (new queue)
// MODE 1: A = ct_f16, B(k) = pool[tp_row[k]]          (targets_prime)
// Block: 256 thr (4 waves). M=256, N-tile 64, K chunked by 64 through LDS.
// Epilogue: stage 256x32 score chunks in LDS (col-major, stride 257), each
// thread keeps top-KS of its row over this block's 64 cols, writes packed
// (valbits<<32 | col) candidates to cand[row][blk][j].
template<int MODE, int KS>
__global__ __launch_bounds__(256) void gemm_topk_kernel(
    const float* __restrict__ queue, const float* __restrict__ pool,
    const float* __restrict__ t_f32, const _Float16* __restrict__ A_f16,
    const int* __restrict__ tp_row, unsigned long long* __restrict__ cand)
{
  // union: B_lds (64*72 f16 = 9216 B) during K-loop, sc (32*257 f32 = 32896 B) in epilogue
  __shared__ __align__(16) char smem[32 * 257 * 4];
  _Float16* B_lds = (_Float16*)smem;
  float*    sc    = (float*)smem;

  const int tid  = threadIdx.x;
  const int lane = tid & 63;
  const int w    = tid >> 6;
  const int quad = lane >> 4;
  const int l15  = lane & 15;
  const long col0 = (long)blockIdx.x * 64;

  // B staging assignment: thread -> (row 0..63, 16-float chunk 0..3)
  const int brow = tid >> 2;
  const int bch  = tid & 3;
  const long gcol = col0 + brow;
  const float* bsrc;
  if (MODE == 0) {
    bsrc = (gcol < B_SZ) ? (t_f32 + gcol * D_SZ) : (queue + gcol * D_SZ);
  } else {
    bsrc = pool + (long)tp_row[gcol] * D_SZ;
  }
  bsrc += bch * 16;

  f32x4 acc[4][4];
  #pragma unroll
  for (int mt = 0; mt < 4; ++mt)
    #pragma unroll
    for (int nt = 0; nt < 4; ++nt) acc[mt][nt] = (f32x4){0.f, 0.f, 0.f, 0.f};

  // A-frag base: A[m = w*64 + mt*16 + l15][k = kc + ks*32 + quad*8 .. +7]
  const _Float16* arow = A_f16 + (long)(w * 64 + l15) * D_SZ + quad * 8;

  // T14 async-stage split: preload kc=0, issue kc+64 loads between barriers
  float4 f0 = *(const float4*)(bsrc + 0);
  float4 f1 = *(const float4*)(bsrc + 4);
  float4 f2 = *(const float4*)(bsrc + 8);
  float4 f3 = *(const float4*)(bsrc + 12);

  #pragma unroll 1
  for (int kc = 0; kc < D_SZ; kc += 64) {
    f16x8 w0, w1;
    w0[0] = (_Float16)f0.x; w0[1] = (_Float16)f0.y; w0[2] = (_Float16)f0.z; w0[3] = (_Float16)f0.w;
    w0[4] = (_Float16)f1.x; w0[5] = (_Float16)f1.y; w0[6] = (_Float16)f1.z; w0[7] = (_Float16)f1.w;
    w1[0] = (_Float16)f2.x; w1[1] = (_Float16)f2.y; w1[2] = (_Float16)f2.z; w1[3] = (_Float16)f2.w;
    w1[4] = (_Float16)f3.x; w1[5] = (_Float16)f3.y; w1[6] = (_Float16)f3.z; w1[7] = (_Float16)f3.w;
    *(f16x8*)(&B_lds[brow * 72 + bch * 16])     = w0;
    *(f16x8*)(&B_lds[brow * 72 + bch * 16 + 8]) = w1;
    __syncthreads();
    if (kc + 64 < D_SZ) {   // next chunk's loads in flight under the MFMAs
      f0 = *(const float4*)(bsrc + kc + 64);
      f1 = *(const float4*)(bsrc + kc + 68);
      f2 = *(const float4*)(bsrc + kc + 72);
      f3 = *(const float4*)(bsrc + kc + 76);
    }
    #pragma unroll
    for (int ks = 0; ks < 2; ++ks) {
      f16x8 af[4], bfr[4];
      #pragma unroll
      for (int mt = 0; mt < 4; ++mt)
        af[mt] = *(const f16x8*)(arow + (long)mt * 16 * D_SZ + kc + ks * 32);
      #pragma unroll
      for (int nt = 0; nt < 4; ++nt)
        bfr[nt] = *(const f16x8*)(&B_lds[(nt * 16 + l15) * 72 + ks * 32 + quad * 8]);
      #pragma unroll
      for (int mt = 0; mt < 4; ++mt)
        #pragma unroll
        for (int nt = 0; nt < 4; ++nt)
          acc[mt][nt] = __builtin_amdgcn_mfma_f32_16x16x32_f16(af[mt], bfr[nt], acc[mt][nt], 0, 0, 0);
    }
    __syncthreads();
  }

  // ---- epilogue: per-row top-KS over this block's 64 cols ----
  // C layout: row = w*64 + mt*16 + quad*4 + i, col = nt*16 + l15 (m89/m91)
  float bv[KS]; int bi[KS];
  #pragma unroll
  for (int j = 0; j < KS; ++j) { bv[j] = -3.4e38f; bi[j] = 0x7fffffff; }
  const int row = tid;
  #pragma unroll 1
  for (int ch = 0; ch < 2; ++ch) {
    __syncthreads();   // smem free (B_lds / previous chunk scan done)
    #pragma unroll
    for (int mt = 0; mt < 4; ++mt) {
      int r0 = w * 64 + mt * 16 + quad * 4;
      #pragma unroll
      for (int nt2 = 0; nt2 < 2; ++nt2) {
        int lc = nt2 * 16 + l15;               // local col 0..31
        #pragma unroll
        for (int i = 0; i < 4; ++i)
          sc[lc * 257 + r0 + i] = acc[mt][ch * 2 + nt2][i];
      }
    }
    __syncthreads();
    int cbase = (int)col0 + ch * 32;
    #pragma unroll 1
    for (int c8 = 0; c8 < 32; c8 += 8) {
      float v[8];
      #pragma unroll
      for (int u = 0; u < 8; ++u) v[u] = sc[(c8 + u) * 257 + row];  // conflict-free (consecutive lanes)
      #pragma unroll
      for (int u = 0; u < 8; ++u) {
        float vv = v[u];
        if (vv > bv[KS - 1]) {   // ascending col scan: strict > keeps smaller idx on ties
          bv[KS - 1] = vv; bi[KS - 1] = cbase + c8 + u;
          #pragma unroll
          for (int m = KS - 1; m > 0; --m) {
            if (bv[m] > bv[m - 1]) {
              float tv = bv[m]; bv[m] = bv[m - 1]; bv[m - 1] = tv;
              int   ti = bi[m]; bi[m] = bi[m - 1]; bi[m - 1] = ti;
            }
          }
        }
      }
    }
  }
  // cand[row][blk][j] — merge kernel reads each row contiguously
  unsigned long long* cp = cand + ((long)row * NBLK + blockIdx.x) * KS;
  #pragma unroll
  for (int j = 0; j < KS; ++j)
    cp[j] = ((unsigned long long)__float_as_uint(bv[j]) << 32) | (unsigned)bi[j];
}

// ---------------- merge: per-row top-K over 2000*KS candidates ----------------
template<int KS>
__global__ __launch_bounds__(256) void merge_topk_kernel(
    const unsigned long long* __restrict__ cand, int* __restrict__ out_idx)
{
  __shared__ float sv[256 * KS];
  __shared__ int   si[256 * KS];
  const int r = blockIdx.x;
  const int tid = threadIdx.x;
  const int TOT = NBLK * KS;
  float bv[KS]; int bi[KS];
  #pragma unroll
  for (int j = 0; j < KS; ++j) { bv[j] = -3.4e38f; bi[j] = 0x7fffffff; }
  const unsigned long long* base = cand + (long)r * TOT;
  #pragma unroll 1
  for (int f = tid; f < TOT; f += 256) {       // coalesced 8B reads
    unsigned long long p = base[f];
    float v = __uint_as_float((unsigned)(p >> 32));
    int   x = (int)(unsigned)p;
    // thread stream is idx-ascending across blocks -> strict > keeps smaller idx
    if (v > bv[KS - 1]) {
      bv[KS - 1] = v; bi[KS - 1] = x;
      #pragma unroll
      for (int m = KS - 1; m > 0; --m) {
        if (bv[m] > bv[m - 1]) {
          float tv = bv[m]; bv[m] = bv[m - 1]; bv[m - 1] = tv;
          int   ti = bi[m]; bi[m] = bi[m - 1]; bi[m - 1] = ti;
        }
      }
    }
  }
  #pragma unroll
  for (int j = 0; j < KS; ++j) { sv[tid * KS + j] = bv[j]; si[tid * KS + j] = bi[j]; }
  for (int s = 128; s > 0; s >>= 1) {
    __syncthreads();
    if (tid < s) {
      int pa = tid * KS, pb = (tid + s) * KS;
      float mv[KS]; int mi[KS];
      int ia = 0, ib = 0;
      #pragma unroll
      for (int j = 0; j < KS; ++j) {
        float va = sv[pa + ia], vb = sv[pb + ib];
        int   xa = si[pa + ia], xb = si[pb + ib];
        bool ta = (va > vb) || (va == vb && xa < xb);
        mv[j] = ta ? va : vb; mi[j] = ta ? xa : xb;
        if (ta) ++ia; else ++ib;
      }
      #pragma unroll
      for (int j = 0; j < KS; ++j) { sv[pa + j] = mv[j]; si[pa + j] = mi[j]; }
    }
  }
  __syncthreads();
  if (tid < KS) out_idx[r * KS + tid] = si[tid];
}

// ---------------- finalize: exact fp32 distances at selected cols, loss+purity ----------------
__global__ __launch_bounds__(256) void finalize_kernel(
    const float* __restrict__ t_f32, const float* __restrict__ q_f32,
    const float* __restrict__ queue,
    const int* __restrict__ un_idx, const int* __restrict__ idxp,
    const int* __restrict__ labels_bank, const int* __restrict__ labels,
    float* __restrict__ out)
{
  __shared__ float red[4];
  __shared__ float dvals[10];
  __shared__ int   csel[5];
  const int b = blockIdx.x;
  const int tid = threadIdx.x;
  const float* trow = t_f32 + (long)b * D_SZ;
  const float* qrow = q_f32 + (long)b * D_SZ;

  // dist_t at the 10 constrained columns (new-queue rows: col<256 -> t)
  #pragma unroll 1
  for (int j = 0; j < 10; ++j) {
    int c = idxp[b * 10 + j];
    const float* cp = (c < B_SZ) ? (t_f32 + (long)c * D_SZ) : (queue + (long)c * D_SZ);
    float p = trow[tid] * cp[tid] + trow[tid + 256] * cp[tid + 256];
    float s = block_sum(p, red);
    if (tid == 0) dvals[j] = 2.f - 2.f * s;
  }
  __syncthreads();
  // pick 5 of 10 by (dist_t asc, idx asc) — equals ref's top_k after the -5 scatter
  if (tid == 0) {
    unsigned used = 0;
    for (int m = 0; m < 5; ++m) {
      int best = -1; float bd = 0.f; int bc = 0;
      for (int j = 0; j < 10; ++j) {
        if (used & (1u << j)) continue;
        float dj = dvals[j]; int cj = idxp[b * 10 + j];
        if (best < 0 || dj < bd || (dj == bd && cj < bc)) { best = j; bd = dj; bc = cj; }
      }
      used |= 1u << best;
      csel[m] = idxp[b * 10 + best];
    }
  }
  __syncthreads();

  float con_s = 0.f, un_s = 0.f;
  #pragma unroll 1
  for (int m = 0; m < 5; ++m) {
    int c = csel[m];
    const float* cp = (c < B_SZ) ? (t_f32 + (long)c * D_SZ) : (queue + (long)c * D_SZ);
    float p = qrow[tid] * cp[tid] + qrow[tid + 256] * cp[tid + 256];
    con_s += block_sum(p, red);
  }
  int match = 0;
  #pragma unroll 1
  for (int m = 0; m < 5; ++m) {
    int c = un_idx[b * 5 + m];
    const float* cp = (c < B_SZ) ? (t_f32 + (long)c * D_SZ) : (queue + (long)c * D_SZ);
    float p = qrow[tid] * cp[tid] + qrow[tid + 256] * cp[tid + 256];
    un_s += block_sum(p, red);
    if (tid == 0) {
      int lb = (c < B_SZ) ? labels[c] : labels_bank[c];   // labels_bank[:B] = labels
      match += (lb == labels[b]) ? 1 : 0;
    }
  }
  if (tid == 0) {
    float con_sum = 10.f - 2.f * con_s;   // sum of 5 x (2-2s)
    float un_sum  = 10.f - 2.f * un_s;
    float lossc = (con_sum * 0.2f + un_sum * 0.2f) * 0.5f * (1.f / 256.f);
    atomicAdd(out + 0, lossc);
    atomicAdd(out + 1, (float)match * 0.2f * (1.f / 256.f));
  }
}

// ---------------- launch ----------------
extern "C" void kernel_launch(void* const* d_in, const int* in_sizes, int n_in,
                              void* d_out, int out_size, void* d_ws, size_t ws_size,
                              hipStream_t stream) {
  const float* query       = (const float*)d_in[0];
  const float* ctar        = (const float*)d_in[1];
  const float* queue       = (const float*)d_in[2];
  const float* pool        = (const float*)d_in[3];
  const int*   labels_bank = (const int*)d_in[4];
  const int*   index_queue = (const int*)d_in[5];
  const int*   pool_qindex = (const int*)d_in[6];
  const int*   labels      = (const int*)d_in[7];
  const int*   indices     = (const int*)d_in[8];

  char* ws = (char*)d_ws;
  float*     t_f32  = (float*)(ws + OFF_T);
  float*     q_f32  = (float*)(ws + OFF_Q);
  _Float16*  t_f16  = (_Float16*)(ws + OFF_TH);
  _Float16*  ct_f16 = (_Float16*)(ws + OFF_CTH);
  int*       new_pq = (int*)(ws + OFF_NPQ);
  int*       tp_row = (int*)(ws + OFF_TPROW);
  int*       un_idx = (int*)(ws + OFF_UN);
  int*       idxp   = (int*)(ws + OFF_IDXP);
  unsigned long long* cand = (unsigned long long*)(ws + OFF_SC);
  float*     out    = (float*)d_out;

  hipMemsetAsync(out, 0, 2 * sizeof(float), stream);

  prep_rows_kernel<<<B_SZ, 256, 0, stream>>>(query, ctar, pool, pool_qindex, indices,
                                             t_f32, q_f32, t_f16, ct_f16);
  prep_newpq_kernel<<<(N_SZ + 255) / 256, 256, 0, stream>>>(pool_qindex, new_pq);
  prep_flip_kernel<<<1, 256, 0, stream>>>(pool_qindex, indices, new_pq);
  prep_tprow_kernel<<<K_SZ / 256, 256, 0, stream>>>(new_pq, index_queue, indices, tp_row);

  gemm_topk_kernel<0, 5><<<NBLK, 256, 0, stream>>>(queue, pool, t_f32, t_f16, tp_row, cand);
  merge_topk_kernel<5><<<B_SZ, 256, 0, stream>>>(cand, un_idx);

  gemm_topk_kernel<1, 10><<<NBLK, 256, 0, stream>>>(queue, pool, t_f32, ct_f16, tp_row, cand);
  merge_topk_kernel<10><<<B_SZ, 256, 0, stream>>>(cand, idxp);

  finalize_kernel<<<B_SZ, 256, 0, stream>>>(t_f32, q_f32, queue, un_idx, idxp,
                                            labels_bank, labels, out);
}

// Round 2
// 944.473 us; speedup vs baseline: 1.3313x; 1.3313x over previous
//
#include <hip/hip_runtime.h>
#include <math.h>

// Problem dims (fixed by setup_inputs)
#define B_SZ 256
#define D_SZ 512
#define K_SZ 128000
#define N_SZ 100000
#define NBLK (K_SZ / 64)   // 2000 gemm blocks, 64 cols each

// Workspace layout (bytes).
#define OFF_T     0UL          // t_f32      [256*512] f32
#define OFF_Q     524288UL     // q_f32      [256*512] f32
#define OFF_TH    1048576UL    // t_f16      [256*512] f16
#define OFF_CTH   1310720UL    // ct_f16     [256*512] f16
#define OFF_NPQ   1572864UL    // new_pq     [100000] i32
#define OFF_TPROW 1973248UL    // tp_row     [128000] i32
#define OFF_UN    2485248UL    // un_idx     [256*5] i32
#define OFF_IDXP  2490880UL    // idxp       [256*10] i32
#define OFF_SC    2501632UL    // cand       [2000][256][<=10] u64 (max 41 MB)

typedef __attribute__((ext_vector_type(4))) float    f32x4;
typedef __attribute__((ext_vector_type(8))) _Float16 f16x8;

// ---------------- block-wide sum over 256 threads ----------------
__device__ __forceinline__ float block_sum(float v, float* red) {
  #pragma unroll
  for (int o = 32; o > 0; o >>= 1) v += __shfl_down(v, o, 64);
  const int w = threadIdx.x >> 6;
  const int l = threadIdx.x & 63;
  __syncthreads();                 // protect red[] reuse across calls
  if (l == 0) red[w] = v;
  __syncthreads();
  return red[0] + red[1] + red[2] + red[3];
}

// ---------------- prep: normalize q,t; gather ct_prime ----------------
__global__ __launch_bounds__(256) void prep_rows_kernel(
    const float* __restrict__ query, const float* __restrict__ ctar,
    const float* __restrict__ pool, const int* __restrict__ pool_qindex,
    const int* __restrict__ indices,
    float* __restrict__ t_f32, float* __restrict__ q_f32,
    _Float16* __restrict__ t_f16, _Float16* __restrict__ ct_f16)
{
  __shared__ float red[4];
  const int b = blockIdx.x, tid = threadIdx.x;
  const long base = (long)b * D_SZ;
  float x0 = query[base + tid], x1 = query[base + 256 + tid];
  float y0 = ctar[base + tid],  y1 = ctar[base + 256 + tid];
  float sq = block_sum(x0 * x0 + x1 * x1, red);
  float st = block_sum(y0 * y0 + y1 * y1, red);
  float rq = 1.f / sqrtf(sq);
  float rt = 1.f / sqrtf(st);
  q_f32[base + tid] = x0 * rq; q_f32[base + 256 + tid] = x1 * rq;
  float t0 = y0 * rt, t1 = y1 * rt;
  t_f32[base + tid] = t0; t_f32[base + 256 + tid] = t1;
  t_f16[base + tid] = (_Float16)t0; t_f16[base + 256 + tid] = (_Float16)t1;
  // ct_prime[b] = pool[1 - pq[indices[b]], indices[b]] (post-flip slot == un-written slot)
  int i = indices[b];
  int slot = 1 - pool_qindex[i];
  const float* pr = pool + ((long)slot * N_SZ + i) * D_SZ;
  ct_f16[base + tid] = (_Float16)pr[tid];
  ct_f16[base + 256 + tid] = (_Float16)pr[tid + 256];
}

__global__ void prep_newpq_kernel(const int* __restrict__ pq, int* __restrict__ new_pq) {
  int i = blockIdx.x * 256 + threadIdx.x;
  if (i < N_SZ) new_pq[i] = pq[i];
}

__global__ void prep_flip_kernel(const int* __restrict__ pq, const int* __restrict__ indices,
                                 int* __restrict__ new_pq) {
  int i = indices[threadIdx.x];           // 1 block x 256; dup indices write same value
  new_pq[i] = 1 - pq[i];
}

__global__ void prep_tprow_kernel(const int* __restrict__ new_pq,
                                  const int* __restrict__ index_queue,
                                  const int* __restrict__ indices,
                                  int* __restrict__ tp_row) {
  int k = blockIdx.x * 256 + threadIdx.x; // 500 blocks -> exactly 128000
  int i = (k < B_SZ) ? indices[k] : index_queue[k];
  tp_row[k] = new_pq[i] * N_SZ + i;
}

// ---------------- fused GEMM + per-block top-K candidates ----------------
// scores[b][k] = rowA(b) . rowB(k)
// MODE 0: A = t_f16, B(k) = (k<256 ? t : queue[k])    (new queue)
// MODE 1: A = ct_f16, B(k) = pool[tp_row[k]]          (targets_prime)
// Block: 256 thr (4 waves). M=256, N-tile 64, K chunked by 64 through LDS.
// Epilogue: stage 256x32 score chunks in LDS (col-major, stride 257), each
// thread keeps top-KS of its row over this block's 64 cols, writes packed
// (valbits<<32 | col) candidates to cand[blk][row][j] (coalesced 20KB/block).
// NOTE (rule #20): acc[][] must ONLY be indexed with compile-time constants,
// else it demotes to scratch (round-1 regression: VGPR=72, +1.05 GB HBM).
// The two 32-col epilogue chunks are therefore explicitly duplicated.
template<int MODE, int KS>
__global__ __launch_bounds__(256) void gemm_topk_kernel(
    const float* __restrict__ queue, const float* __restrict__ pool,
    const float* __restrict__ t_f32, const _Float16* __restrict__ A_f16,
    const int* __restrict__ tp_row, unsigned long long* __restrict__ cand)
{
  // union: B_lds (64*72 f16 = 9216 B) during K-loop, sc (32*257 f32 = 32896 B) in epilogue
  __shared__ __align__(16) char smem[32 * 257 * 4];
  _Float16* B_lds = (_Float16*)smem;
  float*    sc    = (float*)smem;

  const int tid  = threadIdx.x;
  const int lane = tid & 63;
  const int w    = tid >> 6;
  const int quad = lane >> 4;
  const int l15  = lane & 15;
  const long col0 = (long)blockIdx.x * 64;

  // B staging assignment: thread -> (row 0..63, 16-float chunk 0..3)
  const int brow = tid >> 2;
  const int bch  = tid & 3;
  const long gcol = col0 + brow;
  const float* bsrc;
  if (MODE == 0) {
    bsrc = (gcol < B_SZ) ? (t_f32 + gcol * D_SZ) : (queue + gcol * D_SZ);
  } else {
    bsrc = pool + (long)tp_row[gcol] * D_SZ;
  }
  bsrc += bch * 16;

  f32x4 acc[4][4];
  #pragma unroll
  for (int mt = 0; mt < 4; ++mt)
    #pragma unroll
    for (int nt = 0; nt < 4; ++nt) acc[mt][nt] = (f32x4){0.f, 0.f, 0.f, 0.f};

  // A-frag base: A[m = w*64 + mt*16 + l15][k = kc + ks*32 + quad*8 .. +7]
  const _Float16* arow = A_f16 + (long)(w * 64 + l15) * D_SZ + quad * 8;

  // T14 async-stage split: preload kc=0, issue kc+64 loads between barriers
  float4 f0 = *(const float4*)(bsrc + 0);
  float4 f1 = *(const float4*)(bsrc + 4);
  float4 f2 = *(const float4*)(bsrc + 8);
  float4 f3 = *(const float4*)(bsrc + 12);

  #pragma unroll 1
  for (int kc = 0; kc < D_SZ; kc += 64) {
    f16x8 w0, w1;
    w0[0] = (_Float16)f0.x; w0[1] = (_Float16)f0.y; w0[2] = (_Float16)f0.z; w0[3] = (_Float16)f0.w;
    w0[4] = (_Float16)f1.x; w0[5] = (_Float16)f1.y; w0[6] = (_Float16)f1.z; w0[7] = (_Float16)f1.w;
    w1[0] = (_Float16)f2.x; w1[1] = (_Float16)f2.y; w1[2] = (_Float16)f2.z; w1[3] = (_Float16)f2.w;
    w1[4] = (_Float16)f3.x; w1[5] = (_Float16)f3.y; w1[6] = (_Float16)f3.z; w1[7] = (_Float16)f3.w;
    *(f16x8*)(&B_lds[brow * 72 + bch * 16])     = w0;
    *(f16x8*)(&B_lds[brow * 72 + bch * 16 + 8]) = w1;
    __syncthreads();
    if (kc + 64 < D_SZ) {   // next chunk's loads in flight under the MFMAs
      f0 = *(const float4*)(bsrc + kc + 64);
      f1 = *(const float4*)(bsrc + kc + 68);
      f2 = *(const float4*)(bsrc + kc + 72);
      f3 = *(const float4*)(bsrc + kc + 76);
    }
    #pragma unroll
    for (int ks = 0; ks < 2; ++ks) {
      f16x8 af[4], bfr[4];
      #pragma unroll
      for (int mt = 0; mt < 4; ++mt)
        af[mt] = *(const f16x8*)(arow + (long)mt * 16 * D_SZ + kc + ks * 32);
      #pragma unroll
      for (int nt = 0; nt < 4; ++nt)
        bfr[nt] = *(const f16x8*)(&B_lds[(nt * 16 + l15) * 72 + ks * 32 + quad * 8]);
      #pragma unroll
      for (int mt = 0; mt < 4; ++mt)
        #pragma unroll
        for (int nt = 0; nt < 4; ++nt)
          acc[mt][nt] = __builtin_amdgcn_mfma_f32_16x16x32_f16(af[mt], bfr[nt], acc[mt][nt], 0, 0, 0);
    }
    __syncthreads();
  }

  // ---- epilogue: per-row top-KS over this block's 64 cols ----
  // C layout: row = w*64 + mt*16 + quad*4 + i, col = nt*16 + l15 (m89/m91)
  float bv[KS]; int bi[KS];
  #pragma unroll
  for (int j = 0; j < KS; ++j) { bv[j] = -3.4e38f; bi[j] = 0x7fffffff; }
  const int row = tid;

  // ---- chunk 0 (cols 0..31): acc[mt][0..1], all indices compile-time ----
  {
    __syncthreads();
    #pragma unroll
    for (int mt = 0; mt < 4; ++mt) {
      int r0 = w * 64 + mt * 16 + quad * 4;
      #pragma unroll
      for (int nt2 = 0; nt2 < 2; ++nt2) {
        int lc = nt2 * 16 + l15;               // local col 0..31
        #pragma unroll
        for (int i = 0; i < 4; ++i)
          sc[lc * 257 + r0 + i] = acc[mt][nt2][i];
      }
    }
    __syncthreads();
    int cbase = (int)col0;
    #pragma unroll 1
    for (int c8 = 0; c8 < 32; c8 += 8) {
      float v[8];
      #pragma unroll
      for (int u = 0; u < 8; ++u) v[u] = sc[(c8 + u) * 257 + row];  // conflict-free (consecutive lanes)
      #pragma unroll
      for (int u = 0; u < 8; ++u) {
        float vv = v[u];
        if (vv > bv[KS - 1]) {   // ascending col scan: strict > keeps smaller idx on ties
          bv[KS - 1] = vv; bi[KS - 1] = cbase + c8 + u;
          #pragma unroll
          for (int m = KS - 1; m > 0; --m) {
            if (bv[m] > bv[m - 1]) {
              float tv = bv[m]; bv[m] = bv[m - 1]; bv[m - 1] = tv;
              int   ti = bi[m]; bi[m] = bi[m - 1]; bi[m - 1] = ti;
            }
          }
        }
      }
    }
  }
  // ---- chunk 1 (cols 32..63): acc[mt][2..3], all indices compile-time ----
  {
    __syncthreads();
    #pragma unroll
    for (int mt = 0; mt < 4; ++mt) {
      int r0 = w * 64 + mt * 16 + quad * 4;
      #pragma unroll
      for (int nt2 = 0; nt2 < 2; ++nt2) {
        int lc = nt2 * 16 + l15;
        #pragma unroll
        for (int i = 0; i < 4; ++i)
          sc[lc * 257 + r0 + i] = acc[mt][2 + nt2][i];
      }
    }
    __syncthreads();
    int cbase = (int)col0 + 32;
    #pragma unroll 1
    for (int c8 = 0; c8 < 32; c8 += 8) {
      float v[8];
      #pragma unroll
      for (int u = 0; u < 8; ++u) v[u] = sc[(c8 + u) * 257 + row];
      #pragma unroll
      for (int u = 0; u < 8; ++u) {
        float vv = v[u];
        if (vv > bv[KS - 1]) {
          bv[KS - 1] = vv; bi[KS - 1] = cbase + c8 + u;
          #pragma unroll
          for (int m = KS - 1; m > 0; --m) {
            if (bv[m] > bv[m - 1]) {
              float tv = bv[m]; bv[m] = bv[m - 1]; bv[m - 1] = tv;
              int   ti = bi[m]; bi[m] = bi[m - 1]; bi[m - 1] = ti;
            }
          }
        }
      }
    }
  }

  // cand[blk][row][j] — block writes one contiguous, coalesced 256*KS*8 B chunk
  unsigned long long* cp = cand + ((long)blockIdx.x * 256 + row) * KS;
  #pragma unroll
  for (int j = 0; j < KS; ++j)
    cp[j] = ((unsigned long long)__float_as_uint(bv[j]) << 32) | (unsigned)bi[j];
}

// ---------------- merge: per-row top-K over 2000*KS candidates ----------------
template<int KS>
__global__ __launch_bounds__(256) void merge_topk_kernel(
    const unsigned long long* __restrict__ cand, int* __restrict__ out_idx)
{
  __shared__ float sv[256 * KS];
  __shared__ int   si[256 * KS];
  const int r = blockIdx.x;
  const int tid = threadIdx.x;
  float bv[KS]; int bi[KS];
  #pragma unroll
  for (int j = 0; j < KS; ++j) { bv[j] = -3.4e38f; bi[j] = 0x7fffffff; }
  // cand layout [blk][row][j]; per-thread stream is (blk asc, j asc) ->
  // equal-value candidates appear smaller-idx first, strict > keeps them.
  #pragma unroll 1
  for (int blk = tid; blk < NBLK; blk += 256) {
    const unsigned long long* cp = cand + ((long)blk * 256 + r) * KS;
    #pragma unroll
    for (int j = 0; j < KS; ++j) {
      unsigned long long p = cp[j];
      float v = __uint_as_float((unsigned)(p >> 32));
      int   x = (int)(unsigned)p;
      if (v > bv[KS - 1]) {
        bv[KS - 1] = v; bi[KS - 1] = x;
        #pragma unroll
        for (int m = KS - 1; m > 0; --m) {
          if (bv[m] > bv[m - 1]) {
            float tv = bv[m]; bv[m] = bv[m - 1]; bv[m - 1] = tv;
            int   ti = bi[m]; bi[m] = bi[m - 1]; bi[m - 1] = ti;
          }
        }
      }
    }
  }
  #pragma unroll
  for (int j = 0; j < KS; ++j) { sv[tid * KS + j] = bv[j]; si[tid * KS + j] = bi[j]; }
  for (int s = 128; s > 0; s >>= 1) {
    __syncthreads();
    if (tid < s) {
      int pa = tid * KS, pb = (tid + s) * KS;
      float mv[KS]; int mi[KS];
      int ia = 0, ib = 0;
      #pragma unroll
      for (int j = 0; j < KS; ++j) {
        float va = sv[pa + ia], vb = sv[pb + ib];
        int   xa = si[pa + ia], xb = si[pb + ib];
        bool ta = (va > vb) || (va == vb && xa < xb);
        mv[j] = ta ? va : vb; mi[j] = ta ? xa : xb;
        if (ta) ++ia; else ++ib;
      }
      #pragma unroll
      for (int j = 0; j < KS; ++j) { sv[pa + j] = mv[j]; si[pa + j] = mi[j]; }
    }
  }
  __syncthreads();
  if (tid < KS) out_idx[r * KS + tid] = si[tid];
}

// ---------------- finalize: exact fp32 distances at selected cols, loss+purity ----------------
__global__ __launch_bounds__(256) void finalize_kernel(
    const float* __restrict__ t_f32, const float* __restrict__ q_f32,
    const float* __restrict__ queue,
    const int* __restrict__ un_idx, const int* __restrict__ idxp,
    const int* __restrict__ labels_bank, const int* __restrict__ labels,
    float* __restrict__ out)
{
  __shared__ float red[4];
  __shared__ float dvals[10];
  __shared__ int   csel[5];
  const int b = blockIdx.x;
  const int tid = threadIdx.x;
  const float* trow = t_f32 + (long)b * D_SZ;
  const float* qrow = q_f32 + (long)b * D_SZ;

  // dist_t at the 10 constrained columns (new-queue rows: col<256 -> t)
  #pragma unroll 1
  for (int j = 0; j < 10; ++j) {
    int c = idxp[b * 10 + j];
    const float* cp = (c < B_SZ) ? (t_f32 + (long)c * D_SZ) : (queue + (long)c * D_SZ);
    float p = trow[tid] * cp[tid] + trow[tid + 256] * cp[tid + 256];
    float s = block_sum(p, red);
    if (tid == 0) dvals[j] = 2.f - 2.f * s;
  }
  __syncthreads();
  // pick 5 of 10 by (dist_t asc, idx asc) — equals ref's top_k after the -5 scatter
  if (tid == 0) {
    unsigned used = 0;
    for (int m = 0; m < 5; ++m) {
      int best = -1; float bd = 0.f; int bc = 0;
      for (int j = 0; j < 10; ++j) {
        if (used & (1u << j)) continue;
        float dj = dvals[j]; int cj = idxp[b * 10 + j];
        if (best < 0 || dj < bd || (dj == bd && cj < bc)) { best = j; bd = dj; bc = cj; }
      }
      used |= 1u << best;
      csel[m] = idxp[b * 10 + best];
    }
  }
  __syncthreads();

  float con_s = 0.f, un_s = 0.f;
  #pragma unroll 1
  for (int m = 0; m < 5; ++m) {
    int c = csel[m];
    const float* cp = (c < B_SZ) ? (t_f32 + (long)c * D_SZ) : (queue + (long)c * D_SZ);
    float p = qrow[tid] * cp[tid] + qrow[tid + 256] * cp[tid + 256];
    con_s += block_sum(p, red);
  }
  int match = 0;
  #pragma unroll 1
  for (int m = 0; m < 5; ++m) {
    int c = un_idx[b * 5 + m];
    const float* cp = (c < B_SZ) ? (t_f32 + (long)c * D_SZ) : (queue + (long)c * D_SZ);
    float p = qrow[tid] * cp[tid] + qrow[tid + 256] * cp[tid + 256];
    un_s += block_sum(p, red);
    if (tid == 0) {
      int lb = (c < B_SZ) ? labels[c] : labels_bank[c];   // labels_bank[:B] = labels
      match += (lb == labels[b]) ? 1 : 0;
    }
  }
  if (tid == 0) {
    float con_sum = 10.f - 2.f * con_s;   // sum of 5 x (2-2s)
    float un_sum  = 10.f - 2.f * un_s;
    float lossc = (con_sum * 0.2f + un_sum * 0.2f) * 0.5f * (1.f / 256.f);
    atomicAdd(out + 0, lossc);
    atomicAdd(out + 1, (float)match * 0.2f * (1.f / 256.f));
  }
}

// ---------------- launch ----------------
extern "C" void kernel_launch(void* const* d_in, const int* in_sizes, int n_in,
                              void* d_out, int out_size, void* d_ws, size_t ws_size,
                              hipStream_t stream) {
  const float* query       = (const float*)d_in[0];
  const float* ctar        = (const float*)d_in[1];
  const float* queue       = (const float*)d_in[2];
  const float* pool        = (const float*)d_in[3];
  const int*   labels_bank = (const int*)d_in[4];
  const int*   index_queue = (const int*)d_in[5];
  const int*   pool_qindex = (const int*)d_in[6];
  const int*   labels      = (const int*)d_in[7];
  const int*   indices     = (const int*)d_in[8];

  char* ws = (char*)d_ws;
  float*     t_f32  = (float*)(ws + OFF_T);
  float*     q_f32  = (float*)(ws + OFF_Q);
  _Float16*  t_f16  = (_Float16*)(ws + OFF_TH);
  _Float16*  ct_f16 = (_Float16*)(ws + OFF_CTH);
  int*       new_pq = (int*)(ws + OFF_NPQ);
  int*       tp_row = (int*)(ws + OFF_TPROW);
  int*       un_idx = (int*)(ws + OFF_UN);
  int*       idxp   = (int*)(ws + OFF_IDXP);
  unsigned long long* cand = (unsigned long long*)(ws + OFF_SC);
  float*     out    = (float*)d_out;

  hipMemsetAsync(out, 0, 2 * sizeof(float), stream);

  prep_rows_kernel<<<B_SZ, 256, 0, stream>>>(query, ctar, pool, pool_qindex, indices,
                                             t_f32, q_f32, t_f16, ct_f16);
  prep_newpq_kernel<<<(N_SZ + 255) / 256, 256, 0, stream>>>(pool_qindex, new_pq);
  prep_flip_kernel<<<1, 256, 0, stream>>>(pool_qindex, indices, new_pq);
  prep_tprow_kernel<<<K_SZ / 256, 256, 0, stream>>>(new_pq, index_queue, indices, tp_row);

  gemm_topk_kernel<0, 5><<<NBLK, 256, 0, stream>>>(queue, pool, t_f32, t_f16, tp_row, cand);
  merge_topk_kernel<5><<<B_SZ, 256, 0, stream>>>(cand, un_idx);

  gemm_topk_kernel<1, 10><<<NBLK, 256, 0, stream>>>(queue, pool, t_f32, ct_f16, tp_row, cand);
  merge_topk_kernel<10><<<B_SZ, 256, 0, stream>>>(cand, idxp);

  finalize_kernel<<<B_SZ, 256, 0, stream>>>(t_f32, q_f32, queue, un_idx, idxp,
                                            labels_bank, labels, out);
}

// Round 3
// 877.993 us; speedup vs baseline: 1.4321x; 1.0757x over previous
//
#include <hip/hip_runtime.h>
#include <math.h>

// Problem dims (fixed by setup_inputs)
#define B_SZ 256
#define D_SZ 512
#define K_SZ 128000
#define N_SZ 100000
#define NBLK (K_SZ / 64)   // 2000 gemm blocks per mode, 64 cols each

// Workspace layout (bytes).
#define OFF_T     0UL          // t_f32      [256*512] f32
#define OFF_Q     524288UL     // q_f32      [256*512] f32
#define OFF_TH    1048576UL    // t_f16      [256*512] f16
#define OFF_CTH   1310720UL    // ct_f16     [256*512] f16
#define OFF_NPQ   1572864UL    // new_pq     [100000] i32
#define OFF_TPROW 1973248UL    // tp_row     [128000] i32
#define OFF_UN    2485248UL    // un_idx     [256*5] i32
#define OFF_IDXP  2490880UL    // idxp       [256*10] i32
#define OFF_SC    2501632UL    // cand0      [2000][256][5]  u64 (20.48 MB)
#define OFF_SC2   22981632UL   // cand1      [2000][256][10] u64 (40.96 MB)

typedef __attribute__((ext_vector_type(4))) float    f32x4;
typedef __attribute__((ext_vector_type(8))) _Float16 f16x8;

// ---------------- block-wide sum over 256 threads ----------------
__device__ __forceinline__ float block_sum(float v, float* red) {
  #pragma unroll
  for (int o = 32; o > 0; o >>= 1) v += __shfl_down(v, o, 64);
  const int w = threadIdx.x >> 6;
  const int l = threadIdx.x & 63;
  __syncthreads();                 // protect red[] reuse across calls
  if (l == 0) red[w] = v;
  __syncthreads();
  return red[0] + red[1] + red[2] + red[3];
}

// ---------------- prep: normalize q,t; gather ct_prime ----------------
__global__ __launch_bounds__(256) void prep_rows_kernel(
    const float* __restrict__ query, const float* __restrict__ ctar,
    const float* __restrict__ pool, const int* __restrict__ pool_qindex,
    const int* __restrict__ indices,
    float* __restrict__ t_f32, float* __restrict__ q_f32,
    _Float16* __restrict__ t_f16, _Float16* __restrict__ ct_f16)
{
  __shared__ float red[4];
  const int b = blockIdx.x, tid = threadIdx.x;
  const long base = (long)b * D_SZ;
  float x0 = query[base + tid], x1 = query[base + 256 + tid];
  float y0 = ctar[base + tid],  y1 = ctar[base + 256 + tid];
  float sq = block_sum(x0 * x0 + x1 * x1, red);
  float st = block_sum(y0 * y0 + y1 * y1, red);
  float rq = 1.f / sqrtf(sq);
  float rt = 1.f / sqrtf(st);
  q_f32[base + tid] = x0 * rq; q_f32[base + 256 + tid] = x1 * rq;
  float t0 = y0 * rt, t1 = y1 * rt;
  t_f32[base + tid] = t0; t_f32[base + 256 + tid] = t1;
  t_f16[base + tid] = (_Float16)t0; t_f16[base + 256 + tid] = (_Float16)t1;
  // ct_prime[b] = pool[1 - pq[indices[b]], indices[b]] (post-flip slot == un-written slot)
  int i = indices[b];
  int slot = 1 - pool_qindex[i];
  const float* pr = pool + ((long)slot * N_SZ + i) * D_SZ;
  ct_f16[base + tid] = (_Float16)pr[tid];
  ct_f16[base + 256 + tid] = (_Float16)pr[tid + 256];
}

__global__ void prep_newpq_kernel(const int* __restrict__ pq, int* __restrict__ new_pq) {
  int i = blockIdx.x * 256 + threadIdx.x;
  if (i < N_SZ) new_pq[i] = pq[i];
}

__global__ void prep_flip_kernel(const int* __restrict__ pq, const int* __restrict__ indices,
                                 int* __restrict__ new_pq) {
  int i = indices[threadIdx.x];           // 1 block x 256; dup indices write same value
  new_pq[i] = 1 - pq[i];
}

__global__ void prep_tprow_kernel(const int* __restrict__ new_pq,
                                  const int* __restrict__ index_queue,
                                  const int* __restrict__ indices,
                                  int* __restrict__ tp_row) {
  int k = blockIdx.x * 256 + threadIdx.x; // 500 blocks -> exactly 128000
  int i = (k < B_SZ) ? indices[k] : index_queue[k];
  tp_row[k] = new_pq[i] * N_SZ + i;
}

// ---------------- fused GEMM + per-block top-K candidates ----------------
// scores[b][k] = rowA(b) . rowB(k)
// MODE 0: A = t_f16, B(k) = (k<256 ? t : queue[k])    (new queue)
// MODE 1: A = ct_f16, B(k) = pool[tp_row[k]]          (targets_prime)
// Block: 256 thr (4 waves). M=256, N-tile 64, K chunked by 64 through LDS.
// Epilogue: stage 256x32 score chunks in LDS (col-major, stride 257), each
// thread keeps top-KS of its row over this block's 64 cols, writes packed
// (valbits<<32 | col) candidates to cand[blk][row][j] (coalesced 20KB/block).
// NOTE (rule #20): acc[][] must ONLY be indexed with compile-time constants,
// else it demotes to scratch (round-1 regression: VGPR=72, +1.05 GB HBM).
// The two 32-col epilogue chunks are therefore explicitly duplicated.
template<int MODE, int KS>
__device__ __forceinline__ void gemm_topk_body(
    const float* __restrict__ queue, const float* __restrict__ pool,
    const float* __restrict__ t_f32, const _Float16* __restrict__ A_f16,
    const int* __restrict__ tp_row, unsigned long long* __restrict__ cand,
    char* smem, int bid)
{
  // union: B_lds (64*72 f16 = 9216 B) during K-loop, sc (32*257 f32 = 32896 B) in epilogue
  _Float16* B_lds = (_Float16*)smem;
  float*    sc    = (float*)smem;

  const int tid  = threadIdx.x;
  const int lane = tid & 63;
  const int w    = tid >> 6;
  const int quad = lane >> 4;
  const int l15  = lane & 15;
  const long col0 = (long)bid * 64;

  // B staging assignment: thread -> (row 0..63, 16-float chunk 0..3)
  const int brow = tid >> 2;
  const int bch  = tid & 3;
  const long gcol = col0 + brow;
  const float* bsrc;
  if (MODE == 0) {
    bsrc = (gcol < B_SZ) ? (t_f32 + gcol * D_SZ) : (queue + gcol * D_SZ);
  } else {
    bsrc = pool + (long)tp_row[gcol] * D_SZ;
  }
  bsrc += bch * 16;

  f32x4 acc[4][4];
  #pragma unroll
  for (int mt = 0; mt < 4; ++mt)
    #pragma unroll
    for (int nt = 0; nt < 4; ++nt) acc[mt][nt] = (f32x4){0.f, 0.f, 0.f, 0.f};

  // A-frag base: A[m = w*64 + mt*16 + l15][k = kc + ks*32 + quad*8 .. +7]
  const _Float16* arow = A_f16 + (long)(w * 64 + l15) * D_SZ + quad * 8;

  // T14 async-stage split: preload kc=0, issue kc+64 loads between barriers
  float4 f0 = *(const float4*)(bsrc + 0);
  float4 f1 = *(const float4*)(bsrc + 4);
  float4 f2 = *(const float4*)(bsrc + 8);
  float4 f3 = *(const float4*)(bsrc + 12);

  #pragma unroll 1
  for (int kc = 0; kc < D_SZ; kc += 64) {
    f16x8 w0, w1;
    w0[0] = (_Float16)f0.x; w0[1] = (_Float16)f0.y; w0[2] = (_Float16)f0.z; w0[3] = (_Float16)f0.w;
    w0[4] = (_Float16)f1.x; w0[5] = (_Float16)f1.y; w0[6] = (_Float16)f1.z; w0[7] = (_Float16)f1.w;
    w1[0] = (_Float16)f2.x; w1[1] = (_Float16)f2.y; w1[2] = (_Float16)f2.z; w1[3] = (_Float16)f2.w;
    w1[4] = (_Float16)f3.x; w1[5] = (_Float16)f3.y; w1[6] = (_Float16)f3.z; w1[7] = (_Float16)f3.w;
    *(f16x8*)(&B_lds[brow * 72 + bch * 16])     = w0;
    *(f16x8*)(&B_lds[brow * 72 + bch * 16 + 8]) = w1;
    __syncthreads();
    if (kc + 64 < D_SZ) {   // next chunk's loads in flight under the MFMAs
      f0 = *(const float4*)(bsrc + kc + 64);
      f1 = *(const float4*)(bsrc + kc + 68);
      f2 = *(const float4*)(bsrc + kc + 72);
      f3 = *(const float4*)(bsrc + kc + 76);
    }
    #pragma unroll
    for (int ks = 0; ks < 2; ++ks) {
      f16x8 af[4], bfr[4];
      #pragma unroll
      for (int mt = 0; mt < 4; ++mt)
        af[mt] = *(const f16x8*)(arow + (long)mt * 16 * D_SZ + kc + ks * 32);
      #pragma unroll
      for (int nt = 0; nt < 4; ++nt)
        bfr[nt] = *(const f16x8*)(&B_lds[(nt * 16 + l15) * 72 + ks * 32 + quad * 8]);
      #pragma unroll
      for (int mt = 0; mt < 4; ++mt)
        #pragma unroll
        for (int nt = 0; nt < 4; ++nt)
          acc[mt][nt] = __builtin_amdgcn_mfma_f32_16x16x32_f16(af[mt], bfr[nt], acc[mt][nt], 0, 0, 0);
    }
    __syncthreads();
  }

  // ---- epilogue: per-row top-KS over this block's 64 cols ----
  // C layout: row = w*64 + mt*16 + quad*4 + i, col = nt*16 + l15 (m89/m91)
  float bv[KS]; int bi[KS];
  #pragma unroll
  for (int j = 0; j < KS; ++j) { bv[j] = -3.4e38f; bi[j] = 0x7fffffff; }
  const int row = tid;

  // ---- chunk 0 (cols 0..31): acc[mt][0..1], all indices compile-time ----
  {
    __syncthreads();
    #pragma unroll
    for (int mt = 0; mt < 4; ++mt) {
      int r0 = w * 64 + mt * 16 + quad * 4;
      #pragma unroll
      for (int nt2 = 0; nt2 < 2; ++nt2) {
        int lc = nt2 * 16 + l15;               // local col 0..31
        #pragma unroll
        for (int i = 0; i < 4; ++i)
          sc[lc * 257 + r0 + i] = acc[mt][nt2][i];
      }
    }
    __syncthreads();
    int cbase = (int)col0;
    #pragma unroll 1
    for (int c8 = 0; c8 < 32; c8 += 8) {
      float v[8];
      #pragma unroll
      for (int u = 0; u < 8; ++u) v[u] = sc[(c8 + u) * 257 + row];  // conflict-free (consecutive lanes)
      #pragma unroll
      for (int u = 0; u < 8; ++u) {
        float vv = v[u];
        if (vv > bv[KS - 1]) {   // ascending col scan: strict > keeps smaller idx on ties
          bv[KS - 1] = vv; bi[KS - 1] = cbase + c8 + u;
          #pragma unroll
          for (int m = KS - 1; m > 0; --m) {
            if (bv[m] > bv[m - 1]) {
              float tv = bv[m]; bv[m] = bv[m - 1]; bv[m - 1] = tv;
              int   ti = bi[m]; bi[m] = bi[m - 1]; bi[m - 1] = ti;
            }
          }
        }
      }
    }
  }
  // ---- chunk 1 (cols 32..63): acc[mt][2..3], all indices compile-time ----
  {
    __syncthreads();
    #pragma unroll
    for (int mt = 0; mt < 4; ++mt) {
      int r0 = w * 64 + mt * 16 + quad * 4;
      #pragma unroll
      for (int nt2 = 0; nt2 < 2; ++nt2) {
        int lc = nt2 * 16 + l15;
        #pragma unroll
        for (int i = 0; i < 4; ++i)
          sc[lc * 257 + r0 + i] = acc[mt][2 + nt2][i];
      }
    }
    __syncthreads();
    int cbase = (int)col0 + 32;
    #pragma unroll 1
    for (int c8 = 0; c8 < 32; c8 += 8) {
      float v[8];
      #pragma unroll
      for (int u = 0; u < 8; ++u) v[u] = sc[(c8 + u) * 257 + row];
      #pragma unroll
      for (int u = 0; u < 8; ++u) {
        float vv = v[u];
        if (vv > bv[KS - 1]) {
          bv[KS - 1] = vv; bi[KS - 1] = cbase + c8 + u;
          #pragma unroll
          for (int m = KS - 1; m > 0; --m) {
            if (bv[m] > bv[m - 1]) {
              float tv = bv[m]; bv[m] = bv[m - 1]; bv[m - 1] = tv;
              int   ti = bi[m]; bi[m] = bi[m - 1]; bi[m - 1] = ti;
            }
          }
        }
      }
    }
  }

  // cand[blk][row][j] — block writes one contiguous, coalesced 256*KS*8 B chunk
  unsigned long long* cp = cand + ((long)bid * 256 + row) * KS;
  #pragma unroll
  for (int j = 0; j < KS; ++j)
    cp[j] = ((unsigned long long)__float_as_uint(bv[j]) << 32) | (unsigned)bi[j];
}

// Fused launch: blocks [0,2000) = mode0/KS5, [2000,4000) = mode1/KS10.
// Branch is block-uniform; single shared-memory buffer serves both paths.
__global__ __launch_bounds__(256) void gemm_fused_kernel(
    const float* __restrict__ queue, const float* __restrict__ pool,
    const float* __restrict__ t_f32,
    const _Float16* __restrict__ t_f16, const _Float16* __restrict__ ct_f16,
    const int* __restrict__ tp_row,
    unsigned long long* __restrict__ cand0, unsigned long long* __restrict__ cand1)
{
  __shared__ __align__(16) char smem[32 * 257 * 4];
  const int bid = blockIdx.x;
  if (bid < NBLK) {
    gemm_topk_body<0, 5>(queue, pool, t_f32, t_f16, tp_row, cand0, smem, bid);
  } else {
    gemm_topk_body<1, 10>(queue, pool, t_f32, ct_f16, tp_row, cand1, smem, bid - NBLK);
  }
}

// ---------------- merge: per-row top-K over 2000*KS candidates ----------------
template<int KS>
__device__ __forceinline__ void merge_topk_body(
    const unsigned long long* __restrict__ cand, int* __restrict__ out_idx,
    float* sv, int* si, int r)
{
  const int tid = threadIdx.x;
  float bv[KS]; int bi[KS];
  #pragma unroll
  for (int j = 0; j < KS; ++j) { bv[j] = -3.4e38f; bi[j] = 0x7fffffff; }
  // cand layout [blk][row][j]; per-thread stream is (blk asc, j asc) ->
  // equal-value candidates appear smaller-idx first, strict > keeps them.
  #pragma unroll 1
  for (int blk = tid; blk < NBLK; blk += 256) {
    const unsigned long long* cp = cand + ((long)blk * 256 + r) * KS;
    #pragma unroll
    for (int j = 0; j < KS; ++j) {
      unsigned long long p = cp[j];
      float v = __uint_as_float((unsigned)(p >> 32));
      int   x = (int)(unsigned)p;
      if (v > bv[KS - 1]) {
        bv[KS - 1] = v; bi[KS - 1] = x;
        #pragma unroll
        for (int m = KS - 1; m > 0; --m) {
          if (bv[m] > bv[m - 1]) {
            float tv = bv[m]; bv[m] = bv[m - 1]; bv[m - 1] = tv;
            int   ti = bi[m]; bi[m] = bi[m - 1]; bi[m - 1] = ti;
          }
        }
      }
    }
  }
  #pragma unroll
  for (int j = 0; j < KS; ++j) { sv[tid * KS + j] = bv[j]; si[tid * KS + j] = bi[j]; }
  for (int s = 128; s > 0; s >>= 1) {
    __syncthreads();
    if (tid < s) {
      int pa = tid * KS, pb = (tid + s) * KS;
      float mv[KS]; int mi[KS];
      int ia = 0, ib = 0;
      #pragma unroll
      for (int j = 0; j < KS; ++j) {
        float va = sv[pa + ia], vb = sv[pb + ib];
        int   xa = si[pa + ia], xb = si[pb + ib];
        bool ta = (va > vb) || (va == vb && xa < xb);
        mv[j] = ta ? va : vb; mi[j] = ta ? xa : xb;
        if (ta) ++ia; else ++ib;
      }
      #pragma unroll
      for (int j = 0; j < KS; ++j) { sv[pa + j] = mv[j]; si[pa + j] = mi[j]; }
    }
  }
  __syncthreads();
  if (tid < KS) out_idx[r * KS + tid] = si[tid];
}

// Fused merge: blocks [0,256) = KS5 on cand0 -> un_idx; [256,512) = KS10 on cand1 -> idxp.
__global__ __launch_bounds__(256) void merge_fused_kernel(
    const unsigned long long* __restrict__ cand0,
    const unsigned long long* __restrict__ cand1,
    int* __restrict__ un_idx, int* __restrict__ idxp)
{
  __shared__ float sv[256 * 10];
  __shared__ int   si[256 * 10];
  const int bid = blockIdx.x;
  if (bid < 256) {
    merge_topk_body<5>(cand0, un_idx, sv, si, bid);
  } else {
    merge_topk_body<10>(cand1, idxp, sv, si, bid - 256);
  }
}

// ---------------- finalize: exact fp32 distances at selected cols, loss+purity ----------------
__global__ __launch_bounds__(256) void finalize_kernel(
    const float* __restrict__ t_f32, const float* __restrict__ q_f32,
    const float* __restrict__ queue,
    const int* __restrict__ un_idx, const int* __restrict__ idxp,
    const int* __restrict__ labels_bank, const int* __restrict__ labels,
    float* __restrict__ out)
{
  __shared__ float red[4];
  __shared__ float dvals[10];
  __shared__ int   csel[5];
  const int b = blockIdx.x;
  const int tid = threadIdx.x;
  const float* trow = t_f32 + (long)b * D_SZ;
  const float* qrow = q_f32 + (long)b * D_SZ;

  // dist_t at the 10 constrained columns (new-queue rows: col<256 -> t)
  #pragma unroll 1
  for (int j = 0; j < 10; ++j) {
    int c = idxp[b * 10 + j];
    const float* cp = (c < B_SZ) ? (t_f32 + (long)c * D_SZ) : (queue + (long)c * D_SZ);
    float p = trow[tid] * cp[tid] + trow[tid + 256] * cp[tid + 256];
    float s = block_sum(p, red);
    if (tid == 0) dvals[j] = 2.f - 2.f * s;
  }
  __syncthreads();
  // pick 5 of 10 by (dist_t asc, idx asc) — equals ref's top_k after the -5 scatter
  if (tid == 0) {
    unsigned used = 0;
    for (int m = 0; m < 5; ++m) {
      int best = -1; float bd = 0.f; int bc = 0;
      for (int j = 0; j < 10; ++j) {
        if (used & (1u << j)) continue;
        float dj = dvals[j]; int cj = idxp[b * 10 + j];
        if (best < 0 || dj < bd || (dj == bd && cj < bc)) { best = j; bd = dj; bc = cj; }
      }
      used |= 1u << best;
      csel[m] = idxp[b * 10 + best];
    }
  }
  __syncthreads();

  float con_s = 0.f, un_s = 0.f;
  #pragma unroll 1
  for (int m = 0; m < 5; ++m) {
    int c = csel[m];
    const float* cp = (c < B_SZ) ? (t_f32 + (long)c * D_SZ) : (queue + (long)c * D_SZ);
    float p = qrow[tid] * cp[tid] + qrow[tid + 256] * cp[tid + 256];
    con_s += block_sum(p, red);
  }
  int match = 0;
  #pragma unroll 1
  for (int m = 0; m < 5; ++m) {
    int c = un_idx[b * 5 + m];
    const float* cp = (c < B_SZ) ? (t_f32 + (long)c * D_SZ) : (queue + (long)c * D_SZ);
    float p = qrow[tid] * cp[tid] + qrow[tid + 256] * cp[tid + 256];
    un_s += block_sum(p, red);
    if (tid == 0) {
      int lb = (c < B_SZ) ? labels[c] : labels_bank[c];   // labels_bank[:B] = labels
      match += (lb == labels[b]) ? 1 : 0;
    }
  }
  if (tid == 0) {
    float con_sum = 10.f - 2.f * con_s;   // sum of 5 x (2-2s)
    float un_sum  = 10.f - 2.f * un_s;
    float lossc = (con_sum * 0.2f + un_sum * 0.2f) * 0.5f * (1.f / 256.f);
    atomicAdd(out + 0, lossc);
    atomicAdd(out + 1, (float)match * 0.2f * (1.f / 256.f));
  }
}

// ---------------- launch ----------------
extern "C" void kernel_launch(void* const* d_in, const int* in_sizes, int n_in,
                              void* d_out, int out_size, void* d_ws, size_t ws_size,
                              hipStream_t stream) {
  const float* query       = (const float*)d_in[0];
  const float* ctar        = (const float*)d_in[1];
  const float* queue       = (const float*)d_in[2];
  const float* pool        = (const float*)d_in[3];
  const int*   labels_bank = (const int*)d_in[4];
  const int*   index_queue = (const int*)d_in[5];
  const int*   pool_qindex = (const int*)d_in[6];
  const int*   labels      = (const int*)d_in[7];
  const int*   indices     = (const int*)d_in[8];

  char* ws = (char*)d_ws;
  float*     t_f32  = (float*)(ws + OFF_T);
  float*     q_f32  = (float*)(ws + OFF_Q);
  _Float16*  t_f16  = (_Float16*)(ws + OFF_TH);
  _Float16*  ct_f16 = (_Float16*)(ws + OFF_CTH);
  int*       new_pq = (int*)(ws + OFF_NPQ);
  int*       tp_row = (int*)(ws + OFF_TPROW);
  int*       un_idx = (int*)(ws + OFF_UN);
  int*       idxp   = (int*)(ws + OFF_IDXP);
  unsigned long long* cand0 = (unsigned long long*)(ws + OFF_SC);
  unsigned long long* cand1 = (unsigned long long*)(ws + OFF_SC2);
  float*     out    = (float*)d_out;

  hipMemsetAsync(out, 0, 2 * sizeof(float), stream);

  prep_rows_kernel<<<B_SZ, 256, 0, stream>>>(query, ctar, pool, pool_qindex, indices,
                                             t_f32, q_f32, t_f16, ct_f16);
  prep_newpq_kernel<<<(N_SZ + 255) / 256, 256, 0, stream>>>(pool_qindex, new_pq);
  prep_flip_kernel<<<1, 256, 0, stream>>>(pool_qindex, indices, new_pq);
  prep_tprow_kernel<<<K_SZ / 256, 256, 0, stream>>>(new_pq, index_queue, indices, tp_row);

  gemm_fused_kernel<<<2 * NBLK, 256, 0, stream>>>(queue, pool, t_f32, t_f16, ct_f16,
                                                  tp_row, cand0, cand1);
  merge_fused_kernel<<<512, 256, 0, stream>>>(cand0, cand1, un_idx, idxp);

  finalize_kernel<<<B_SZ, 256, 0, stream>>>(t_f32, q_f32, queue, un_idx, idxp,
                                            labels_bank, labels, out);
}